// Round 1
// baseline (1114.323 us; speedup 1.0000x reference)
//
#include <hip/hip_runtime.h>

#define B_ROWS 65536
#define C_COLS 1000
#define C_PAD  1024
#define D_DIM  128

typedef __attribute__((ext_vector_type(8))) short short8;
typedef __attribute__((ext_vector_type(4))) float f32x4;

__device__ __forceinline__ unsigned short f32_to_bf16(float f) {
  unsigned int u = __float_as_uint(f);
  u += 0x7fffu + ((u >> 16) & 1u);
  return (unsigned short)(u >> 16);
}
__device__ __forceinline__ float bf16_to_f32(unsigned short h) {
  return __uint_as_float(((unsigned int)h) << 16);
}

// Pre-split centers into bf16 hi/lo + fp32 c_sq (padded to 1024 rows).
__global__ void prep_centers(const float* __restrict__ centers,
                             unsigned short* __restrict__ c_hi,
                             unsigned short* __restrict__ c_lo,
                             float* __restrict__ c_sq) {
  int row = blockIdx.x * blockDim.x + threadIdx.x;
  if (row >= C_PAD) return;
  if (row < C_COLS) {
    float s = 0.f;
    #pragma unroll 4
    for (int k = 0; k < D_DIM; ++k) {
      float v = centers[row * D_DIM + k];
      unsigned short h = f32_to_bf16(v);
      unsigned short l = f32_to_bf16(v - bf16_to_f32(h));
      c_hi[row * D_DIM + k] = h;
      c_lo[row * D_DIM + k] = l;
      s += v * v;
    }
    c_sq[row] = s;
  } else {
    #pragma unroll 4
    for (int k = 0; k < D_DIM; ++k) { c_hi[row*D_DIM+k] = 0; c_lo[row*D_DIM+k] = 0; }
    c_sq[row] = 1e30f;  // pad cols -> logits ~ -5e29 -> exp underflows to 0
  }
}

// One block = 16 rows x all 1024 (padded) cols. 4 waves split cols (256 each).
// Split-bf16 MFMA cross-term GEMM, softmax fully in registers, fused 3-output write.
__global__ void centroid_fused(const float* __restrict__ x,
                               const unsigned short* __restrict__ c_hi,
                               const unsigned short* __restrict__ c_lo,
                               const float* __restrict__ c_sq,
                               float* __restrict__ out) {
  const int lane = threadIdx.x & 63;
  const int wave = threadIdx.x >> 6;
  const int row0 = blockIdx.x * 16;
  const int arow = lane & 15;   // A-frag row / output col-in-tile
  const int kgrp = lane >> 4;   // 0..3

  __shared__ float xsq_lds[16];
  __shared__ float redm[4][16];
  __shared__ float reds[4][16];

  // ---- Load A rows (shared by all 4 waves), split to bf16 hi/lo, x_sq on the fly
  short8 ah[4], al[4];
  float sumsq = 0.f;
  const float* xrow = x + (size_t)(row0 + arow) * D_DIM;
  #pragma unroll
  for (int s = 0; s < 4; ++s) {
    const float* p = xrow + s * 32 + kgrp * 8;
    float4 v0 = *reinterpret_cast<const float4*>(p);
    float4 v1 = *reinterpret_cast<const float4*>(p + 4);
    const float vals[8] = {v0.x, v0.y, v0.z, v0.w, v1.x, v1.y, v1.z, v1.w};
    short8 h, l;
    #pragma unroll
    for (int j = 0; j < 8; ++j) {
      float xv = vals[j];
      sumsq += xv * xv;
      unsigned short hb = f32_to_bf16(xv);
      unsigned short lb = f32_to_bf16(xv - bf16_to_f32(hb));
      h[j] = (short)hb;
      l[j] = (short)lb;
    }
    ah[s] = h; al[s] = l;
  }
  // row sum-of-squares: reduce across the 4 k-groups (lanes ^16, ^32)
  sumsq += __shfl_xor(sumsq, 16);
  sumsq += __shfl_xor(sumsq, 32);
  if (wave == 0 && lane < 16) xsq_lds[lane] = sumsq;  // lanes 0..15 hold rows 0..15
  __syncthreads();

  // ---- GEMM: per wave, 16 col-tiles of 16; 3 split MFMAs per k-slice
  f32x4 acc[16];
  #pragma unroll
  for (int t = 0; t < 16; ++t) acc[t] = (f32x4){0.f, 0.f, 0.f, 0.f};

  const int colbase = wave * 256;
  #pragma unroll
  for (int t = 0; t < 16; ++t) {
    const int col = colbase + t * 16 + arow;
    const unsigned short* bhp = c_hi + (size_t)col * D_DIM + kgrp * 8;
    const unsigned short* blp = c_lo + (size_t)col * D_DIM + kgrp * 8;
    #pragma unroll
    for (int s = 0; s < 4; ++s) {
      short8 bh = *reinterpret_cast<const short8*>(bhp + s * 32);
      short8 bl = *reinterpret_cast<const short8*>(blp + s * 32);
      acc[t] = __builtin_amdgcn_mfma_f32_16x16x32_bf16(ah[s], bh, acc[t], 0, 0, 0);
      acc[t] = __builtin_amdgcn_mfma_f32_16x16x32_bf16(al[s], bh, acc[t], 0, 0, 0);
      acc[t] = __builtin_amdgcn_mfma_f32_16x16x32_bf16(ah[s], bl, acc[t], 0, 0, 0);
    }
  }

  // ---- Finalize logits = cross - 0.5*(x_sq + c_sq). Output row = kgrp*4+r, col = arow.
  float xsq_r[4];
  #pragma unroll
  for (int r = 0; r < 4; ++r) xsq_r[r] = xsq_lds[kgrp * 4 + r];
  #pragma unroll
  for (int t = 0; t < 16; ++t) {
    float csq = c_sq[colbase + t * 16 + arow];
    #pragma unroll
    for (int r = 0; r < 4; ++r)
      acc[t][r] = acc[t][r] - 0.5f * (xsq_r[r] + csq);
  }

  // ---- Row max (within wave strip: over 16 tiles, then across the 16 cols)
  float m[4];
  #pragma unroll
  for (int r = 0; r < 4; ++r) m[r] = -3.0e38f;
  #pragma unroll
  for (int t = 0; t < 16; ++t)
    #pragma unroll
    for (int r = 0; r < 4; ++r) m[r] = fmaxf(m[r], acc[t][r]);
  #pragma unroll
  for (int mask = 1; mask < 16; mask <<= 1)
    #pragma unroll
    for (int r = 0; r < 4; ++r) m[r] = fmaxf(m[r], __shfl_xor(m[r], mask));
  if ((lane & 15) == 0)
    #pragma unroll
    for (int r = 0; r < 4; ++r) redm[wave][kgrp * 4 + r] = m[r];
  __syncthreads();
  #pragma unroll
  for (int r = 0; r < 4; ++r) {
    int row = kgrp * 4 + r;
    m[r] = fmaxf(fmaxf(redm[0][row], redm[1][row]), fmaxf(redm[2][row], redm[3][row]));
  }

  // ---- Row sum of exp(logit - m)
  float sm[4] = {0.f, 0.f, 0.f, 0.f};
  #pragma unroll
  for (int t = 0; t < 16; ++t)
    #pragma unroll
    for (int r = 0; r < 4; ++r) sm[r] += __expf(acc[t][r] - m[r]);
  #pragma unroll
  for (int mask = 1; mask < 16; mask <<= 1)
    #pragma unroll
    for (int r = 0; r < 4; ++r) sm[r] += __shfl_xor(sm[r], mask);
  if ((lane & 15) == 0)
    #pragma unroll
    for (int r = 0; r < 4; ++r) reds[wave][kgrp * 4 + r] = sm[r];
  __syncthreads();
  float lse[4];
  #pragma unroll
  for (int r = 0; r < 4; ++r) {
    int row = kgrp * 4 + r;
    float S = reds[0][row] + reds[1][row] + reds[2][row] + reds[3][row];
    lse[r] = m[r] + __logf(S);
  }

  // ---- Fused write of logits / conf / log_conf
  float* out_logits  = out;
  float* out_conf    = out + (size_t)B_ROWS * C_COLS;
  float* out_logconf = out + 2 * (size_t)B_ROWS * C_COLS;
  #pragma unroll
  for (int t = 0; t < 16; ++t) {
    const int col = colbase + t * 16 + arow;
    if (col < C_COLS) {
      #pragma unroll
      for (int r = 0; r < 4; ++r) {
        const size_t idx = (size_t)(row0 + kgrp * 4 + r) * C_COLS + col;
        const float lg = acc[t][r];
        const float lc = lg - lse[r];
        out_logits[idx]  = lg;
        out_logconf[idx] = lc;
        out_conf[idx]    = __expf(lc);
      }
    }
  }
}

extern "C" void kernel_launch(void* const* d_in, const int* in_sizes, int n_in,
                              void* d_out, int out_size, void* d_ws, size_t ws_size,
                              hipStream_t stream) {
  const float* x       = (const float*)d_in[0];
  const float* centers = (const float*)d_in[1];
  float* out = (float*)d_out;

  // workspace layout: c_hi [1024*128 u16] | c_lo [1024*128 u16] | c_sq [1024 f32]
  unsigned short* c_hi = (unsigned short*)d_ws;
  unsigned short* c_lo = c_hi + (size_t)C_PAD * D_DIM;
  float* c_sq = (float*)(c_lo + (size_t)C_PAD * D_DIM);

  prep_centers<<<C_PAD / 256, 256, 0, stream>>>(centers, c_hi, c_lo, c_sq);
  centroid_fused<<<B_ROWS / 16, 256, 0, stream>>>(x, c_hi, c_lo, c_sq, out);
}

// Round 3
// 1081.702 us; speedup vs baseline: 1.0302x; 1.0302x over previous
//
#include <hip/hip_runtime.h>

#define B_ROWS 65536
#define C_COLS 1000
#define C_PAD  1024
#define D_DIM  128

typedef __attribute__((ext_vector_type(8))) short short8;
typedef __attribute__((ext_vector_type(4))) float f32x4;

__device__ __forceinline__ unsigned short f32_to_bf16(float f) {
  unsigned int u = __float_as_uint(f);
  u += 0x7fffu + ((u >> 16) & 1u);
  return (unsigned short)(u >> 16);
}
__device__ __forceinline__ float bf16_to_f32(unsigned short h) {
  return __uint_as_float(((unsigned int)h) << 16);
}

// Pre-split centers into bf16 hi/lo + fp32 c_sq (padded to 1024 rows).
// Fully parallel: 128 blocks x 256 threads; 32 lanes per row, float4 per lane.
__global__ void prep_centers(const float* __restrict__ centers,
                             unsigned short* __restrict__ c_hi,
                             unsigned short* __restrict__ c_lo,
                             float* __restrict__ c_sq) {
  const int tid = threadIdx.x;
  const int row = blockIdx.x * 8 + (tid >> 5);
  const int l32 = tid & 31;
  ushort4 h4, l4;
  float s = 0.f;
  if (row < C_COLS) {
    float4 v = *reinterpret_cast<const float4*>(centers + (size_t)row * D_DIM + l32 * 4);
    const float vals[4] = {v.x, v.y, v.z, v.w};
    unsigned short hs[4], ls[4];
    #pragma unroll
    for (int j = 0; j < 4; ++j) {
      float f = vals[j];
      s += f * f;
      hs[j] = f32_to_bf16(f);
      ls[j] = f32_to_bf16(f - bf16_to_f32(hs[j]));
    }
    h4 = make_ushort4(hs[0], hs[1], hs[2], hs[3]);
    l4 = make_ushort4(ls[0], ls[1], ls[2], ls[3]);
  } else {
    h4 = make_ushort4(0, 0, 0, 0);
    l4 = h4;
  }
  *reinterpret_cast<ushort4*>(c_hi + (size_t)row * D_DIM + l32 * 4) = h4;
  *reinterpret_cast<ushort4*>(c_lo + (size_t)row * D_DIM + l32 * 4) = l4;
  // row sum-of-squares across the 32 lanes of this half-wave (xor<32 stays in half)
  #pragma unroll
  for (int mask = 1; mask < 32; mask <<= 1) s += __shfl_xor(s, mask);
  if (l32 == 0) c_sq[row] = (row < C_COLS) ? s : 1e30f;
}

// One block = 16 rows x all 1024 (padded) cols. 4 waves split cols (256 each).
// mfma(centers, x): per lane -> 4 CONSECUTIVE centers x 1 x-row => float4 stores,
// softmax reduction = in-lane + 2 shuffles + tiny LDS.
__global__ void centroid_fused(const float* __restrict__ x,
                               const unsigned short* __restrict__ c_hi,
                               const unsigned short* __restrict__ c_lo,
                               const float* __restrict__ c_sq,
                               float* __restrict__ out) {
  const int lane = threadIdx.x & 63;
  const int wave = threadIdx.x >> 6;
  const int row0 = blockIdx.x * 16;
  const int xr   = lane & 15;   // x-row in block / center-in-tile for B loads
  const int kgrp = lane >> 4;   // 0..3 (k-chunk id; also center-quad id in output)

  __shared__ float redm[4][16];
  __shared__ float reds[4][16];

  // ---- Load x rows (operand-2 frags), split to bf16 hi/lo, x_sq on the fly
  short8 ah[4], al[4];
  float xsq = 0.f;
  const float* xrow = x + (size_t)(row0 + xr) * D_DIM;
  #pragma unroll
  for (int s = 0; s < 4; ++s) {
    const float* p = xrow + s * 32 + kgrp * 8;
    float4 v0 = *reinterpret_cast<const float4*>(p);
    float4 v1 = *reinterpret_cast<const float4*>(p + 4);
    const float vals[8] = {v0.x, v0.y, v0.z, v0.w, v1.x, v1.y, v1.z, v1.w};
    short8 h, l;
    #pragma unroll
    for (int j = 0; j < 8; ++j) {
      float xv = vals[j];
      xsq += xv * xv;
      unsigned short hb = f32_to_bf16(xv);
      unsigned short lb = f32_to_bf16(xv - bf16_to_f32(hb));
      h[j] = (short)hb;
      l[j] = (short)lb;
    }
    ah[s] = h; al[s] = l;
  }
  // full row sum-of-squares for row (lane&15): reduce across the 4 k-groups
  xsq += __shfl_xor(xsq, 16);
  xsq += __shfl_xor(xsq, 32);

  // ---- GEMM: per wave, 16 col-tiles of 16 centers; swapped-operand MFMA
  f32x4 acc[16];
  #pragma unroll
  for (int t = 0; t < 16; ++t) acc[t] = (f32x4){0.f, 0.f, 0.f, 0.f};

  const int colbase = wave * 256;
  #pragma unroll
  for (int t = 0; t < 16; ++t) {
    const int crow = colbase + t * 16 + xr;           // center index for this lane's frag
    const unsigned short* bhp = c_hi + (size_t)crow * D_DIM + kgrp * 8;
    const unsigned short* blp = c_lo + (size_t)crow * D_DIM + kgrp * 8;
    #pragma unroll
    for (int s = 0; s < 4; ++s) {
      short8 bh = *reinterpret_cast<const short8*>(bhp + s * 32);
      short8 bl = *reinterpret_cast<const short8*>(blp + s * 32);
      acc[t] = __builtin_amdgcn_mfma_f32_16x16x32_bf16(bh, ah[s], acc[t], 0, 0, 0);
      acc[t] = __builtin_amdgcn_mfma_f32_16x16x32_bf16(bh, al[s], acc[t], 0, 0, 0);
      acc[t] = __builtin_amdgcn_mfma_f32_16x16x32_bf16(bl, ah[s], acc[t], 0, 0, 0);
    }
  }

  // ---- Finalize logits = cross - 0.5*(x_sq + c_sq).
  // Lane holds centers c0..c0+3 (c0 = colbase + t*16 + kgrp*4) for x-row (lane&15).
  #pragma unroll
  for (int t = 0; t < 16; ++t) {
    const int c0 = colbase + t * 16 + kgrp * 4;
    const f32x4 csqv = *reinterpret_cast<const f32x4*>(c_sq + c0);
    #pragma unroll
    for (int r = 0; r < 4; ++r)
      acc[t][r] = acc[t][r] - 0.5f * (xsq + csqv[r]);
  }

  // ---- Row max: in-lane over 64 values, then across the 4 k-groups, then 4 waves
  float m = -3.0e38f;
  #pragma unroll
  for (int t = 0; t < 16; ++t)
    #pragma unroll
    for (int r = 0; r < 4; ++r) m = fmaxf(m, acc[t][r]);
  m = fmaxf(m, __shfl_xor(m, 16));
  m = fmaxf(m, __shfl_xor(m, 32));
  if (lane < 16) redm[wave][lane] = m;
  __syncthreads();
  m = fmaxf(fmaxf(redm[0][xr], redm[1][xr]), fmaxf(redm[2][xr], redm[3][xr]));

  // ---- Row sum of exp
  float sm = 0.f;
  #pragma unroll
  for (int t = 0; t < 16; ++t)
    #pragma unroll
    for (int r = 0; r < 4; ++r) sm += __expf(acc[t][r] - m);
  sm += __shfl_xor(sm, 16);
  sm += __shfl_xor(sm, 32);
  if (lane < 16) reds[wave][lane] = sm;
  __syncthreads();
  const float S = reds[0][xr] + reds[1][xr] + reds[2][xr] + reds[3][xr];
  const float lse = m + __logf(S);

  // ---- Fused float4 writes of logits / conf / log_conf
  float* out_logits  = out;
  float* out_conf    = out + (size_t)B_ROWS * C_COLS;
  float* out_logconf = out + 2 * (size_t)B_ROWS * C_COLS;
  const size_t rowoff = (size_t)(row0 + xr) * C_COLS;
  #pragma unroll
  for (int t = 0; t < 16; ++t) {
    const int c0 = colbase + t * 16 + kgrp * 4;
    f32x4 lg, lc, cf;
    #pragma unroll
    for (int r = 0; r < 4; ++r) {
      lg[r] = acc[t][r];
      lc[r] = lg[r] - lse;
      cf[r] = __expf(lc[r]);
    }
    if (c0 + 3 < C_COLS) {
      *reinterpret_cast<f32x4*>(out_logits  + rowoff + c0) = lg;
      *reinterpret_cast<f32x4*>(out_conf    + rowoff + c0) = cf;
      *reinterpret_cast<f32x4*>(out_logconf + rowoff + c0) = lc;
    } else if (c0 < C_COLS) {
      #pragma unroll
      for (int r = 0; r < 4; ++r) {
        if (c0 + r < C_COLS) {
          out_logits [rowoff + c0 + r] = lg[r];
          out_conf   [rowoff + c0 + r] = cf[r];
          out_logconf[rowoff + c0 + r] = lc[r];
        }
      }
    }
  }
}

extern "C" void kernel_launch(void* const* d_in, const int* in_sizes, int n_in,
                              void* d_out, int out_size, void* d_ws, size_t ws_size,
                              hipStream_t stream) {
  const float* x       = (const float*)d_in[0];
  const float* centers = (const float*)d_in[1];
  float* out = (float*)d_out;

  // workspace layout: c_hi [1024*128 u16] | c_lo [1024*128 u16] | c_sq [1024 f32]
  unsigned short* c_hi = (unsigned short*)d_ws;
  unsigned short* c_lo = c_hi + (size_t)C_PAD * D_DIM;
  float* c_sq = (float*)(c_lo + (size_t)C_PAD * D_DIM);

  prep_centers<<<C_PAD / 8, 256, 0, stream>>>(centers, c_hi, c_lo, c_sq);
  centroid_fused<<<B_ROWS / 16, 256, 0, stream>>>(x, c_hi, c_lo, c_sq, out);
}